// Round 2
// baseline (952.412 us; speedup 1.0000x reference)
//
#include <hip/hip_runtime.h>
#include <cstdint>
#include <cstddef>

// ---------------------------------------------------------------------------
// GATAttention: B=8, M=50000, d=256, heads=8, head_dim=32, gsl_hidden=16, k=500
//
//   U[b,h,:]  = sumh[b,:] + sum_{masked m} (exp(A[b,m,h])-1) * h[b,m,:]
//   Z[b,h]    = (M - cnt) + sum_{masked} exp(A[b,m,h])
//   out[b,e]  = normalize(relu( U[b,e>>5,:]@w_w[:,e]/Z + relu(mean_h@res_w+res_b) ))
//
// Round-5: k1 weight reads moved to LDS. Theory: per-kk gw[g] reads were
// per-lane vector loads (not s_load) -> 4096 VMEM + 4096 addr-VALU per
// thread = ~80us of the 103us VALUBusy. Now g1w staged to LDS once per
// block (16 KB), read as 4x ds_read_b128 per kk via one base + offset
// immediates. CH 32->16 keeps LDS at 34 KB (4 blocks/CU). Gate FMA order
// unchanged -> z32 bit-identical -> band/top-k exactness untouched.
// ---------------------------------------------------------------------------

#define MM     50000
#define BATCH  8
#define TILES  196            // ceil(50000/256)
#define CANDCAP 4096
#define COMPCAP 2048

// workspace layout (bytes)
#define OFF_Z      0u                 // float [B*M]        1,600,000
#define OFF_CANDR  1600000u           // int   [B*4096]       131,072
#define OFF_CANDK  1731072u           // u64   [B*4096]       262,144
#define OFF_COMP   1993216u           // int   [B*2048]        65,536
#define OFF_LO     2058752u           // u32   [8]                 32
#define OFF_PAD    2058784u           //                           64
// zeroed block:
#define OFF_SUMH   2058848u           // double [8*256]        16,384
#define OFF_UCORR  2075232u           // double [8*8*256]     131,072
#define OFF_ZCORR  2206304u           // double [8*8]             512
#define OFF_CCNT   2206816u           // int [8]                   32
#define OFF_CANDC  2206848u           // int [8]                   32
#define ZERO_OFF   OFF_SUMH
#define ZERO_SZ    148032u

__device__ __forceinline__ unsigned int f32_sortable(float z) {
    unsigned int u = __float_as_uint(z);
    return (u & 0x80000000u) ? ~u : (u | 0x80000000u);
}

// ---------------------------------------------------------------------------
// k1: stream h. fp32 gate logit + column sums only. Weights from LDS.
// Chunk = 16 columns. Per-wave-private transposed tile (same-wave DS is
// in-order, no barriers in the main loop).
__global__ __launch_bounds__(256) void k1_main(
    const float* __restrict__ h,
    const float* __restrict__ g1w,     // [256][16]
    const float* __restrict__ g1b,     // [16]
    const float* __restrict__ g2w,     // [16]
    const float* __restrict__ g2b,     // [1]
    float* __restrict__ z32,           // [B*M]
    double* __restrict__ sumh)         // [B][256]
{
    __shared__ float tile[4][16][65];     // [wave][kk][row+pad]  16,640 B
    __shared__ float lsum[256];           //                       1,024 B
    __shared__ float wlds[256 * 16];      // g1w staged           16,384 B

    const int tid  = threadIdx.x;
    const int w    = tid >> 6;
    const int lane = tid & 63;
    lsum[tid] = 0.0f;
    // stage g1w into LDS (coalesced float4)
    {
        const float4* g4 = (const float4*)g1w;
        float4*       w4 = (float4*)wlds;
#pragma unroll
        for (int i = 0; i < 4; ++i) w4[tid + 256 * i] = g4[tid + 256 * i];
    }
    __syncthreads();

    const int bid = blockIdx.x;
    const int b   = bid / TILES;
    const int t0  = bid % TILES;
    const int wave_row0 = t0 * 256 + w * 64;
    const size_t bbase = (size_t)b * MM;

    const int subrow = lane >> 2;   // 0..15 : row-within-group-of-16
    const int colq   = lane & 3;    // 0..3  : float4 slot within 16-col chunk

    // per-i row pointers (row = wave_row0 + subrow + 16*i), clamped + validity
    const float* rp[4];
    bool valid[4];
#pragma unroll
    for (int i = 0; i < 4; ++i) {
        const int m = wave_row0 + subrow + 16 * i;
        valid[i] = (m < MM);
        const int mc = valid[i] ? m : (MM - 1);
        rp[i] = h + (bbase + (size_t)mc) * 256 + colq * 4;
    }

    float4 buf[4];

#define K1_LOAD(cc) do {                                                    \
    _Pragma("unroll")                                                       \
    for (int i = 0; i < 4; ++i) {                                           \
        float4 v = *(const float4*)(rp[i] + (cc) * 16);                     \
        if (!valid[i]) { v.x = 0.f; v.y = 0.f; v.z = 0.f; v.w = 0.f; }      \
        buf[i] = v;                                                         \
    }                                                                       \
} while (0)

    // column partial sums: 4 register adds + 4-level shfl (stride 4/8/16/32)
    // combines the 16 subrows holding the same colq -> 64-row column sums.
#define K1_CSUM(cc) do {                                                    \
    float sx = 0.f, sy = 0.f, sz = 0.f, sw = 0.f;                           \
    _Pragma("unroll")                                                       \
    for (int i = 0; i < 4; ++i) {                                           \
        sx += buf[i].x; sy += buf[i].y; sz += buf[i].z; sw += buf[i].w;     \
    }                                                                       \
    sx += __shfl_xor(sx, 4, 64);  sy += __shfl_xor(sy, 4, 64);              \
    sz += __shfl_xor(sz, 4, 64);  sw += __shfl_xor(sw, 4, 64);              \
    sx += __shfl_xor(sx, 8, 64);  sy += __shfl_xor(sy, 8, 64);              \
    sz += __shfl_xor(sz, 8, 64);  sw += __shfl_xor(sw, 8, 64);              \
    sx += __shfl_xor(sx, 16, 64); sy += __shfl_xor(sy, 16, 64);             \
    sz += __shfl_xor(sz, 16, 64); sw += __shfl_xor(sw, 16, 64);             \
    sx += __shfl_xor(sx, 32, 64); sy += __shfl_xor(sy, 32, 64);             \
    sz += __shfl_xor(sz, 32, 64); sw += __shfl_xor(sw, 32, 64);             \
    if (subrow == 0) {                                                      \
        atomicAdd(&lsum[(cc) * 16 + colq * 4 + 0], sx);                     \
        atomicAdd(&lsum[(cc) * 16 + colq * 4 + 1], sy);                     \
        atomicAdd(&lsum[(cc) * 16 + colq * 4 + 2], sz);                     \
        atomicAdd(&lsum[(cc) * 16 + colq * 4 + 3], sw);                     \
    }                                                                       \
} while (0)

    // transpose into wave-private tile
#define K1_STORE() do {                                                     \
    _Pragma("unroll")                                                       \
    for (int i = 0; i < 4; ++i) {                                           \
        const int rr = subrow + 16 * i;                                     \
        tile[w][colq * 4 + 0][rr] = buf[i].x;                               \
        tile[w][colq * 4 + 1][rr] = buf[i].y;                               \
        tile[w][colq * 4 + 2][rr] = buf[i].z;                               \
        tile[w][colq * 4 + 3][rr] = buf[i].w;                               \
    }                                                                       \
} while (0)

    float gacc[16];
#pragma unroll
    for (int g = 0; g < 16; ++g) gacc[g] = 0.0f;

    // stage chunk 0 (wave-private tile, same-wave DS is in-order)
    K1_LOAD(0);
    K1_CSUM(0);
    K1_STORE();

    for (int c = 0; c < 16; ++c) {
        const bool has = (c < 15);
        if (has) K1_LOAD(c + 1);          // prefetch stays in flight...
        const int k0 = c * 16;
#pragma unroll
        for (int kk = 0; kk < 16; ++kk) {  // ...under the gate FMAs
            const float hv = tile[w][kk][lane];
            // weights from LDS: one base + offset immediates, 4x ds_read_b128
            const float4* wp = (const float4*)(wlds + (k0 + kk) * 16);
            const float4 w0 = wp[0], w1 = wp[1], w2 = wp[2], w3 = wp[3];
            gacc[0]  = fmaf(hv, w0.x, gacc[0]);
            gacc[1]  = fmaf(hv, w0.y, gacc[1]);
            gacc[2]  = fmaf(hv, w0.z, gacc[2]);
            gacc[3]  = fmaf(hv, w0.w, gacc[3]);
            gacc[4]  = fmaf(hv, w1.x, gacc[4]);
            gacc[5]  = fmaf(hv, w1.y, gacc[5]);
            gacc[6]  = fmaf(hv, w1.z, gacc[6]);
            gacc[7]  = fmaf(hv, w1.w, gacc[7]);
            gacc[8]  = fmaf(hv, w2.x, gacc[8]);
            gacc[9]  = fmaf(hv, w2.y, gacc[9]);
            gacc[10] = fmaf(hv, w2.z, gacc[10]);
            gacc[11] = fmaf(hv, w2.w, gacc[11]);
            gacc[12] = fmaf(hv, w3.x, gacc[12]);
            gacc[13] = fmaf(hv, w3.y, gacc[13]);
            gacc[14] = fmaf(hv, w3.z, gacc[14]);
            gacc[15] = fmaf(hv, w3.w, gacc[15]);
        }
        if (has) {            // consume prefetch AFTER all reads of chunk c
            K1_CSUM(c + 1);
            K1_STORE();       // in-order same-wave DS: safe to overwrite
        }
    }

#undef K1_LOAD
#undef K1_CSUM
#undef K1_STORE

    const int m = wave_row0 + lane;
    if (m < MM) {
        float z = g2b[0];
#pragma unroll
        for (int g = 0; g < 16; ++g) {
            float sg = gacc[g] + g1b[g];
            sg = fmaxf(sg, 0.0f);
            z = fmaf(sg, g2w[g], z);
        }
        z32[bbase + m] = z;
    }
    __syncthreads();
    atomicAdd(&sumh[b * 256 + tid], (double)lsum[tid]);
}

// ---------------------------------------------------------------------------
// k2: sampled order statistic -> band cutoff lo (sortable u32)
__global__ __launch_bounds__(1024) void k2_sample(
    const float* __restrict__ z32,
    const int* __restrict__ kptr,
    unsigned int* __restrict__ lo_out)
{
    __shared__ unsigned int buf[1024];
    const int b   = blockIdx.x;
    const int tid = threadIdx.x;
    const size_t base = (size_t)b * MM;
    const int kval = min(*kptr, MM);

    int idx = (int)(((long long)tid * MM) / 1024);
    buf[tid] = f32_sortable(z32[base + idx]);
    __syncthreads();
    for (int sz = 2; sz <= 1024; sz <<= 1)
        for (int j = sz >> 1; j > 0; j >>= 1) {
            __syncthreads();
            int i = tid, ixj = i ^ j;
            if (ixj > i) {
                unsigned int a = buf[i], c = buf[ixj];
                bool up = ((i & sz) == 0);
                if ((up && a > c) || (!up && a < c)) { buf[i] = c; buf[ixj] = a; }
            }
        }
    __syncthreads();
    if (tid == 0) {
        int ks = (int)(((long long)kval * 1024) / MM) + 35;  // ~rank k+1700
        ks = min(1023, max(1, ks));
        lo_out[b] = buf[1023 - ks];
    }
}

// ---------------------------------------------------------------------------
// k3: rows below band -> mask=0; band rows -> candidate list (ballot append)
__global__ __launch_bounds__(256) void k3_band(
    const float* __restrict__ z32,
    const unsigned int* __restrict__ lo_in,
    float* __restrict__ maskout,
    int* __restrict__ cand_cnt,
    int* __restrict__ cand_rows)
{
    int bid = blockIdx.x;
    int b = bid / TILES, t0 = bid % TILES;
    int m = t0 * 256 + threadIdx.x;
    int lane = threadIdx.x & 63;
    bool cand = false;
    if (m < MM) {
        size_t row = (size_t)b * MM + m;
        cand = (f32_sortable(z32[row]) >= lo_in[b]);
        if (!cand) maskout[row] = 0.0f;     // band rows written in k3s
    }
    unsigned long long ball = __ballot(cand);
    int wbase = 0;
    if (lane == 0) { int wc = __popcll(ball); if (wc) wbase = atomicAdd(&cand_cnt[b], wc); }
    wbase = __shfl(wbase, 0, 64);
    if (cand) {
        int pos = wbase + __popcll(ball & ((1ull << lane) - 1ull));
        if (pos < CANDCAP) cand_rows[b * CANDCAP + pos] = m;
    }
}

// ---------------------------------------------------------------------------
// k3r: exact f64 gate recompute for candidates (one thread per candidate)
__global__ __launch_bounds__(256) void k3r_refine(
    const float* __restrict__ h,
    const float* __restrict__ g1w,
    const float* __restrict__ g1b,
    const float* __restrict__ g2w,
    const float* __restrict__ g2b,
    const int* __restrict__ cand_cnt,
    const int* __restrict__ cand_rows,
    unsigned long long* __restrict__ cand_keys)
{
    __shared__ double g1s[256][16];   // 32 KB
    const int b    = blockIdx.x >> 4;
    const int part = blockIdx.x & 15;
    const int tid  = threadIdx.x;
    for (int i = tid; i < 4096; i += 256) g1s[i >> 4][i & 15] = (double)g1w[i];
    __syncthreads();

    const int n = min(cand_cnt[b], CANDCAP);
    const size_t bbase = (size_t)b * MM;
    for (int slot = part * 256 + tid; slot < n; slot += 4096) {
        int row = cand_rows[b * CANDCAP + slot];
        const float* hp = h + (bbase + (size_t)row) * 256;
        double gacc[16];
#pragma unroll
        for (int g = 0; g < 16; ++g) gacc[g] = 0.0;
        for (int k = 0; k < 256; ++k) {
            double hd = (double)hp[k];
#pragma unroll
            for (int g = 0; g < 16; ++g) gacc[g] = fma(hd, g1s[k][g], gacc[g]);
        }
        double z = (double)g2b[0];
#pragma unroll
        for (int g = 0; g < 16; ++g) {
            double sg = gacc[g] + (double)g1b[g];
            sg = sg > 0.0 ? sg : 0.0;
            z = fma(sg, (double)g2w[g], z);
        }
        long long uz = __double_as_longlong(z);
        unsigned long long key = (uz < 0)
            ? ~((unsigned long long)uz)
            : ((unsigned long long)uz | 0x8000000000000000ULL);
        cand_keys[b * CANDCAP + slot] = key;
    }
}

// ---------------------------------------------------------------------------
// k3s: exact kth-largest among candidate f64 keys; write band masks; build
// masked-row compact list.
__global__ __launch_bounds__(1024) void k3s_select(
    const int* __restrict__ kptr,
    const int* __restrict__ cand_cnt,
    const int* __restrict__ cand_rows,
    const unsigned long long* __restrict__ cand_keys,
    float* __restrict__ maskout,
    int* __restrict__ ccnt,
    int* __restrict__ compact)
{
    __shared__ unsigned long long kbuf[CANDCAP];   // 32 KB
    __shared__ int s_cnt;

    const int b    = blockIdx.x;
    const int tid  = threadIdx.x;
    const int lane = tid & 63;
    const int n = min(cand_cnt[b], CANDCAP);
    const size_t bbase = (size_t)b * MM;
    int kval = min(*kptr, MM);
    if (kval > n) kval = n;   // safety (analysis: n ~ 2200 >> k)

    for (int i = tid; i < n; i += 1024) kbuf[i] = cand_keys[b * CANDCAP + i];
    __syncthreads();

    unsigned long long p64 = 0;
    int kk = kval;
    for (int bit = 63; bit >= 0; --bit) {
        if (tid == 0) s_cnt = 0;
        __syncthreads();
        unsigned long long himask = (bit == 63) ? 0ull : (~0ull << (bit + 1));
        int loc = 0;
        for (int i = tid; i < n; i += 1024) {
            unsigned long long x = kbuf[i];
            if (((x ^ p64) & himask) == 0ull && ((x >> bit) & 1ull)) loc++;
        }
        loc += __shfl_xor(loc, 32, 64);
        loc += __shfl_xor(loc, 16, 64);
        loc += __shfl_xor(loc, 8, 64);
        loc += __shfl_xor(loc, 4, 64);
        loc += __shfl_xor(loc, 2, 64);
        loc += __shfl_xor(loc, 1, 64);
        if (lane == 0 && loc) atomicAdd(&s_cnt, loc);
        __syncthreads();
        int c1 = s_cnt;
        if (c1 >= kk) p64 |= (1ull << bit); else kk -= c1;
        __syncthreads();
    }

    // masks + compact list for in-mask rows
    for (int i0 = 0; i0 < n; i0 += 1024) {
        int i = i0 + tid;
        bool active = (i < n);
        bool mk = false;
        int row = 0;
        if (active) {
            row = cand_rows[b * CANDCAP + i];
            mk = (kbuf[i] >= p64);
            maskout[bbase + row] = mk ? 1.0f : 0.0f;
        }
        unsigned long long ball = __ballot(mk);
        int wbase = 0;
        if (lane == 0) { int wc = __popcll(ball); if (wc) wbase = atomicAdd(&ccnt[b], wc); }
        wbase = __shfl(wbase, 0, 64);
        if (mk) {
            int pos = wbase + __popcll(ball & ((1ull << lane) - 1ull));
            if (pos < COMPCAP) compact[b * COMPCAP + pos] = row;
        }
    }
}

// ---------------------------------------------------------------------------
// k4: recompute A for masked rows; Ucorr[b][h][d] += (exp(A)-1)*h; Zcorr.
__global__ __launch_bounds__(256) void k4_corr(
    const float* __restrict__ h,
    const float* __restrict__ att_w,   // [256][8]
    const float* __restrict__ att_b,   // [8]
    const int* __restrict__ compact,
    const int* __restrict__ ccnt,
    double* __restrict__ Ucorr,
    double* __restrict__ Zcorr)
{
    __shared__ float hv_s[256];
    __shared__ float a_s[8];

    const int b    = blockIdx.x >> 5;
    const int part = blockIdx.x & 31;
    const int tid  = threadIdx.x;
    const int head = tid >> 5;
    const int seg  = tid & 31;
    const size_t bbase = (size_t)b * MM;
    const int n = min(ccnt[b], COMPCAP);

    float acc[8], zac[8];
#pragma unroll
    for (int j = 0; j < 8; ++j) { acc[j] = 0.f; zac[j] = 0.f; }

    for (int i = part; i < n; i += 32) {
        int row = compact[b * COMPCAP + i];
        float hv = h[(bbase + (size_t)row) * 256 + tid];
        hv_s[tid] = hv;
        __syncthreads();
        float p = 0.f;
#pragma unroll
        for (int j = 0; j < 8; ++j)
            p = fmaf(hv_s[seg * 8 + j], att_w[(seg * 8 + j) * 8 + head], p);
        p += __shfl_xor(p, 1, 64);
        p += __shfl_xor(p, 2, 64);
        p += __shfl_xor(p, 4, 64);
        p += __shfl_xor(p, 8, 64);
        p += __shfl_xor(p, 16, 64);
        if (seg == 0) a_s[head] = fmaxf(p + att_b[head], 0.f);
        __syncthreads();
#pragma unroll
        for (int j = 0; j < 8; ++j) {
            float w8 = expf(a_s[j]) - 1.0f;
            acc[j] = fmaf(w8, hv, acc[j]);
            zac[j] += w8;
        }
        __syncthreads();
    }
#pragma unroll
    for (int j = 0; j < 8; ++j)
        atomicAdd(&Ucorr[(b * 8 + j) * 256 + tid], (double)acc[j]);
    if (tid == 0) {
#pragma unroll
        for (int j = 0; j < 8; ++j) atomicAdd(&Zcorr[b * 8 + j], (double)zac[j]);
    }
}

// ---------------------------------------------------------------------------
// k5: epilogue
__global__ __launch_bounds__(256) void k5_final(
    const double* __restrict__ sumh,
    const double* __restrict__ Ucorr,
    const double* __restrict__ Zcorr,
    const int* __restrict__ ccnt,
    const float* __restrict__ w_w,     // [256][256]
    const float* __restrict__ res_w,   // [256][256]
    const float* __restrict__ res_b,   // [256]
    float* __restrict__ out0)
{
    __shared__ float Us[8 * 256];
    __shared__ float ms[256];
    __shared__ float red[256];
    __shared__ float s_mean, s_var;

    int b = blockIdx.x, e = threadIdx.x;
    double sh = sumh[b * 256 + e];
    ms[e] = (float)sh;
#pragma unroll
    for (int j = 0; j < 8; ++j)
        Us[j * 256 + e] = (float)(sh + Ucorr[(b * 8 + j) * 256 + e]);
    __syncthreads();

    int hh = e >> 5;
    float Z = (float)((double)(MM - ccnt[b]) + Zcorr[b * 8 + hh]);
    float attn = 0.f, qr = 0.f;
    for (int d = 0; d < 256; ++d) {
        attn = fmaf(Us[hh * 256 + d], w_w[d * 256 + e], attn);
        qr   = fmaf(ms[d],            res_w[d * 256 + e], qr);
    }
    float qres = fmaxf(qr * (1.0f / (float)MM) + res_b[e], 0.f);
    float pre  = fmaxf(attn / Z + qres, 0.f);

    red[e] = pre; __syncthreads();
    for (int s = 128; s > 0; s >>= 1) { if (e < s) red[e] += red[e + s]; __syncthreads(); }
    if (e == 0) s_mean = red[0] * (1.0f / 256.0f);
    __syncthreads();
    float mean = s_mean;
    float dv = pre - mean;
    red[e] = dv * dv; __syncthreads();
    for (int s = 128; s > 0; s >>= 1) { if (e < s) red[e] += red[e + s]; __syncthreads(); }
    if (e == 0) s_var = red[0] * (1.0f / 256.0f);
    __syncthreads();
    out0[b * 256 + e] = dv / sqrtf(s_var + 1e-8f);
}

// ---------------------------------------------------------------------------
extern "C" void kernel_launch(void* const* d_in, const int* in_sizes, int n_in,
                              void* d_out, int out_size, void* d_ws, size_t ws_size,
                              hipStream_t stream) {
    const float* h     = (const float*)d_in[0];
    const float* att_w = (const float*)d_in[1];
    const float* att_b = (const float*)d_in[2];
    const float* w_w   = (const float*)d_in[3];
    const float* res_w = (const float*)d_in[4];
    const float* res_b = (const float*)d_in[5];
    const float* g1w   = (const float*)d_in[6];
    const float* g1b   = (const float*)d_in[7];
    const float* g2w   = (const float*)d_in[8];
    const float* g2b   = (const float*)d_in[9];
    const int*   kptr  = (const int*)d_in[10];

    char* ws = (char*)d_ws;
    float*              z32     = (float*)(ws + OFF_Z);
    int*                candr   = (int*)(ws + OFF_CANDR);
    unsigned long long* candk   = (unsigned long long*)(ws + OFF_CANDK);
    int*                compact = (int*)(ws + OFF_COMP);
    unsigned int*       lo      = (unsigned int*)(ws + OFF_LO);
    double*             sumh    = (double*)(ws + OFF_SUMH);
    double*             Ucorr   = (double*)(ws + OFF_UCORR);
    double*             Zcorr   = (double*)(ws + OFF_ZCORR);
    int*                ccnt    = (int*)(ws + OFF_CCNT);
    int*                candc   = (int*)(ws + OFF_CANDC);

    float* out0    = (float*)d_out;
    float* maskout = out0 + BATCH * 256;

    hipMemsetAsync(ws + ZERO_OFF, 0, ZERO_SZ, stream);

    k1_main   <<<BATCH*TILES, 256,  0, stream>>>(h, g1w, g1b, g2w, g2b, z32, sumh);
    k2_sample <<<BATCH,       1024, 0, stream>>>(z32, kptr, lo);
    k3_band   <<<BATCH*TILES, 256,  0, stream>>>(z32, lo, maskout, candc, candr);
    k3r_refine<<<BATCH*16,    256,  0, stream>>>(h, g1w, g1b, g2w, g2b,
                                                 candc, candr, candk);
    k3s_select<<<BATCH,       1024, 0, stream>>>(kptr, candc, candr, candk,
                                                 maskout, ccnt, compact);
    k4_corr   <<<BATCH*32,    256,  0, stream>>>(h, att_w, att_b, compact, ccnt,
                                                 Ucorr, Zcorr);
    k5_final  <<<BATCH,       256,  0, stream>>>(sumh, Ucorr, Zcorr, ccnt,
                                                 w_w, res_w, res_b, out0);
}

// Round 3
// 800.247 us; speedup vs baseline: 1.1901x; 1.1901x over previous
//
#include <hip/hip_runtime.h>
#include <cstdint>
#include <cstddef>

// ---------------------------------------------------------------------------
// GATAttention: B=8, M=50000, d=256, heads=8, head_dim=32, gsl_hidden=16, k=500
//
//   U[b,h,:]  = sumh[b,:] + sum_{masked m} (exp(A[b,m,h])-1) * h[b,m,:]
//   Z[b,h]    = (M - cnt) + sum_{masked} exp(A[b,m,h])
//   out[b,e]  = normalize(relu( U[b,e>>5,:]@w_w[:,e]/Z + relu(mean_h@res_w+res_b) ))
//
// Round-6: occupancy fix for the LDS-weight k1. Round-2 evidence: VALUBusy
// 40->15.6% proved weights belong on the LDS pipe, but VGPR 68->172 (full
// 16-kk unroll keeping 64 weight regs + hoisted ds_reads live) collapsed
// occupancy to 10.4% -> latency-bound, 325us. Work budgets (FMA 21us,
// LDS ~40us, HBM 65us per CU) are all below the HBM floor, so only
// latency-hiding is missing:
//   1. __launch_bounds__(256,4): cap 128 VGPR -> >=4 waves/SIMD.
//   2. #pragma unroll 2 on kk loop: live weight regs 64 -> ~16-32.
//   3. tile pad 65 -> 66: transpose-store conflicts 4-way -> 2-way (free).
// Gate FMA order unchanged -> z32 bit-identical -> band/top-k exact.
// ---------------------------------------------------------------------------

#define MM     50000
#define BATCH  8
#define TILES  196            // ceil(50000/256)
#define CANDCAP 4096
#define COMPCAP 2048

// workspace layout (bytes)
#define OFF_Z      0u                 // float [B*M]        1,600,000
#define OFF_CANDR  1600000u           // int   [B*4096]       131,072
#define OFF_CANDK  1731072u           // u64   [B*4096]       262,144
#define OFF_COMP   1993216u           // int   [B*2048]        65,536
#define OFF_LO     2058752u           // u32   [8]                 32
#define OFF_PAD    2058784u           //                           64
// zeroed block:
#define OFF_SUMH   2058848u           // double [8*256]        16,384
#define OFF_UCORR  2075232u           // double [8*8*256]     131,072
#define OFF_ZCORR  2206304u           // double [8*8]             512
#define OFF_CCNT   2206816u           // int [8]                   32
#define OFF_CANDC  2206848u           // int [8]                   32
#define ZERO_OFF   OFF_SUMH
#define ZERO_SZ    148032u

__device__ __forceinline__ unsigned int f32_sortable(float z) {
    unsigned int u = __float_as_uint(z);
    return (u & 0x80000000u) ? ~u : (u | 0x80000000u);
}

// ---------------------------------------------------------------------------
// k1: stream h. fp32 gate logit + column sums only. Weights from LDS
// (wave-uniform ds_read_b128 broadcast). Chunk = 16 columns. Per-wave-
// private transposed tile (same-wave DS is in-order, no barriers in loop).
__global__ __launch_bounds__(256, 4) void k1_main(
    const float* __restrict__ h,
    const float* __restrict__ g1w,     // [256][16]
    const float* __restrict__ g1b,     // [16]
    const float* __restrict__ g2w,     // [16]
    const float* __restrict__ g2b,     // [1]
    float* __restrict__ z32,           // [B*M]
    double* __restrict__ sumh)         // [B][256]
{
    __shared__ float tile[4][16][66];     // [wave][kk][row+pad66] 16,896 B
    __shared__ float lsum[256];           //                        1,024 B
    __shared__ float wlds[256 * 16];      // g1w staged            16,384 B

    const int tid  = threadIdx.x;
    const int w    = tid >> 6;
    const int lane = tid & 63;
    lsum[tid] = 0.0f;
    // stage g1w into LDS (coalesced float4)
    {
        const float4* g4 = (const float4*)g1w;
        float4*       w4 = (float4*)wlds;
#pragma unroll
        for (int i = 0; i < 4; ++i) w4[tid + 256 * i] = g4[tid + 256 * i];
    }
    __syncthreads();

    const int bid = blockIdx.x;
    const int b   = bid / TILES;
    const int t0  = bid % TILES;
    const int wave_row0 = t0 * 256 + w * 64;
    const size_t bbase = (size_t)b * MM;

    const int subrow = lane >> 2;   // 0..15 : row-within-group-of-16
    const int colq   = lane & 3;    // 0..3  : float4 slot within 16-col chunk

    // per-i row pointers (row = wave_row0 + subrow + 16*i), clamped + validity
    const float* rp[4];
    bool valid[4];
#pragma unroll
    for (int i = 0; i < 4; ++i) {
        const int m = wave_row0 + subrow + 16 * i;
        valid[i] = (m < MM);
        const int mc = valid[i] ? m : (MM - 1);
        rp[i] = h + (bbase + (size_t)mc) * 256 + colq * 4;
    }

    float4 buf[4];

#define K1_LOAD(cc) do {                                                    \
    _Pragma("unroll")                                                       \
    for (int i = 0; i < 4; ++i) {                                           \
        float4 v = *(const float4*)(rp[i] + (cc) * 16);                     \
        if (!valid[i]) { v.x = 0.f; v.y = 0.f; v.z = 0.f; v.w = 0.f; }      \
        buf[i] = v;                                                         \
    }                                                                       \
} while (0)

    // column partial sums: 4 register adds + 4-level shfl (stride 4/8/16/32)
    // combines the 16 subrows holding the same colq -> 64-row column sums.
#define K1_CSUM(cc) do {                                                    \
    float sx = 0.f, sy = 0.f, sz = 0.f, sw = 0.f;                           \
    _Pragma("unroll")                                                       \
    for (int i = 0; i < 4; ++i) {                                           \
        sx += buf[i].x; sy += buf[i].y; sz += buf[i].z; sw += buf[i].w;     \
    }                                                                       \
    sx += __shfl_xor(sx, 4, 64);  sy += __shfl_xor(sy, 4, 64);              \
    sz += __shfl_xor(sz, 4, 64);  sw += __shfl_xor(sw, 4, 64);              \
    sx += __shfl_xor(sx, 8, 64);  sy += __shfl_xor(sy, 8, 64);              \
    sz += __shfl_xor(sz, 8, 64);  sw += __shfl_xor(sw, 8, 64);              \
    sx += __shfl_xor(sx, 16, 64); sy += __shfl_xor(sy, 16, 64);             \
    sz += __shfl_xor(sz, 16, 64); sw += __shfl_xor(sw, 16, 64);             \
    sx += __shfl_xor(sx, 32, 64); sy += __shfl_xor(sy, 32, 64);             \
    sz += __shfl_xor(sz, 32, 64); sw += __shfl_xor(sw, 32, 64);             \
    if (subrow == 0) {                                                      \
        atomicAdd(&lsum[(cc) * 16 + colq * 4 + 0], sx);                     \
        atomicAdd(&lsum[(cc) * 16 + colq * 4 + 1], sy);                     \
        atomicAdd(&lsum[(cc) * 16 + colq * 4 + 2], sz);                     \
        atomicAdd(&lsum[(cc) * 16 + colq * 4 + 3], sw);                     \
    }                                                                       \
} while (0)

    // transpose into wave-private tile; pad 66: bank = (8*colq+2j+subrow)%32
    // -> worst 2-way aliasing (free on wave64)
#define K1_STORE() do {                                                     \
    _Pragma("unroll")                                                       \
    for (int i = 0; i < 4; ++i) {                                           \
        const int rr = subrow + 16 * i;                                     \
        tile[w][colq * 4 + 0][rr] = buf[i].x;                               \
        tile[w][colq * 4 + 1][rr] = buf[i].y;                               \
        tile[w][colq * 4 + 2][rr] = buf[i].z;                               \
        tile[w][colq * 4 + 3][rr] = buf[i].w;                               \
    }                                                                       \
} while (0)

    float gacc[16];
#pragma unroll
    for (int g = 0; g < 16; ++g) gacc[g] = 0.0f;

    // stage chunk 0 (wave-private tile, same-wave DS is in-order)
    K1_LOAD(0);
    K1_CSUM(0);
    K1_STORE();

    for (int c = 0; c < 16; ++c) {
        const bool has = (c < 15);
        if (has) K1_LOAD(c + 1);          // prefetch stays in flight...
        const int k0 = c * 16;
#pragma unroll 2
        for (int kk = 0; kk < 16; ++kk) {  // ...under the gate FMAs
            const float hv = tile[w][kk][lane];
            // weights from LDS: wave-uniform base -> ds_read_b128 broadcast
            const float4* wp = (const float4*)(wlds + (k0 + kk) * 16);
            const float4 w0 = wp[0], w1 = wp[1], w2 = wp[2], w3 = wp[3];
            gacc[0]  = fmaf(hv, w0.x, gacc[0]);
            gacc[1]  = fmaf(hv, w0.y, gacc[1]);
            gacc[2]  = fmaf(hv, w0.z, gacc[2]);
            gacc[3]  = fmaf(hv, w0.w, gacc[3]);
            gacc[4]  = fmaf(hv, w1.x, gacc[4]);
            gacc[5]  = fmaf(hv, w1.y, gacc[5]);
            gacc[6]  = fmaf(hv, w1.z, gacc[6]);
            gacc[7]  = fmaf(hv, w1.w, gacc[7]);
            gacc[8]  = fmaf(hv, w2.x, gacc[8]);
            gacc[9]  = fmaf(hv, w2.y, gacc[9]);
            gacc[10] = fmaf(hv, w2.z, gacc[10]);
            gacc[11] = fmaf(hv, w2.w, gacc[11]);
            gacc[12] = fmaf(hv, w3.x, gacc[12]);
            gacc[13] = fmaf(hv, w3.y, gacc[13]);
            gacc[14] = fmaf(hv, w3.z, gacc[14]);
            gacc[15] = fmaf(hv, w3.w, gacc[15]);
        }
        if (has) {            // consume prefetch AFTER all reads of chunk c
            K1_CSUM(c + 1);
            K1_STORE();       // in-order same-wave DS: safe to overwrite
        }
    }

#undef K1_LOAD
#undef K1_CSUM
#undef K1_STORE

    const int m = wave_row0 + lane;
    if (m < MM) {
        float z = g2b[0];
#pragma unroll
        for (int g = 0; g < 16; ++g) {
            float sg = gacc[g] + g1b[g];
            sg = fmaxf(sg, 0.0f);
            z = fmaf(sg, g2w[g], z);
        }
        z32[bbase + m] = z;
    }
    __syncthreads();
    atomicAdd(&sumh[b * 256 + tid], (double)lsum[tid]);
}

// ---------------------------------------------------------------------------
// k2: sampled order statistic -> band cutoff lo (sortable u32)
__global__ __launch_bounds__(1024) void k2_sample(
    const float* __restrict__ z32,
    const int* __restrict__ kptr,
    unsigned int* __restrict__ lo_out)
{
    __shared__ unsigned int buf[1024];
    const int b   = blockIdx.x;
    const int tid = threadIdx.x;
    const size_t base = (size_t)b * MM;
    const int kval = min(*kptr, MM);

    int idx = (int)(((long long)tid * MM) / 1024);
    buf[tid] = f32_sortable(z32[base + idx]);
    __syncthreads();
    for (int sz = 2; sz <= 1024; sz <<= 1)
        for (int j = sz >> 1; j > 0; j >>= 1) {
            __syncthreads();
            int i = tid, ixj = i ^ j;
            if (ixj > i) {
                unsigned int a = buf[i], c = buf[ixj];
                bool up = ((i & sz) == 0);
                if ((up && a > c) || (!up && a < c)) { buf[i] = c; buf[ixj] = a; }
            }
        }
    __syncthreads();
    if (tid == 0) {
        int ks = (int)(((long long)kval * 1024) / MM) + 35;  // ~rank k+1700
        ks = min(1023, max(1, ks));
        lo_out[b] = buf[1023 - ks];
    }
}

// ---------------------------------------------------------------------------
// k3: rows below band -> mask=0; band rows -> candidate list (ballot append)
__global__ __launch_bounds__(256) void k3_band(
    const float* __restrict__ z32,
    const unsigned int* __restrict__ lo_in,
    float* __restrict__ maskout,
    int* __restrict__ cand_cnt,
    int* __restrict__ cand_rows)
{
    int bid = blockIdx.x;
    int b = bid / TILES, t0 = bid % TILES;
    int m = t0 * 256 + threadIdx.x;
    int lane = threadIdx.x & 63;
    bool cand = false;
    if (m < MM) {
        size_t row = (size_t)b * MM + m;
        cand = (f32_sortable(z32[row]) >= lo_in[b]);
        if (!cand) maskout[row] = 0.0f;     // band rows written in k3s
    }
    unsigned long long ball = __ballot(cand);
    int wbase = 0;
    if (lane == 0) { int wc = __popcll(ball); if (wc) wbase = atomicAdd(&cand_cnt[b], wc); }
    wbase = __shfl(wbase, 0, 64);
    if (cand) {
        int pos = wbase + __popcll(ball & ((1ull << lane) - 1ull));
        if (pos < CANDCAP) cand_rows[b * CANDCAP + pos] = m;
    }
}

// ---------------------------------------------------------------------------
// k3r: exact f64 gate recompute for candidates (one thread per candidate)
__global__ __launch_bounds__(256) void k3r_refine(
    const float* __restrict__ h,
    const float* __restrict__ g1w,
    const float* __restrict__ g1b,
    const float* __restrict__ g2w,
    const float* __restrict__ g2b,
    const int* __restrict__ cand_cnt,
    const int* __restrict__ cand_rows,
    unsigned long long* __restrict__ cand_keys)
{
    __shared__ double g1s[256][16];   // 32 KB
    const int b    = blockIdx.x >> 4;
    const int part = blockIdx.x & 15;
    const int tid  = threadIdx.x;
    for (int i = tid; i < 4096; i += 256) g1s[i >> 4][i & 15] = (double)g1w[i];
    __syncthreads();

    const int n = min(cand_cnt[b], CANDCAP);
    const size_t bbase = (size_t)b * MM;
    for (int slot = part * 256 + tid; slot < n; slot += 4096) {
        int row = cand_rows[b * CANDCAP + slot];
        const float* hp = h + (bbase + (size_t)row) * 256;
        double gacc[16];
#pragma unroll
        for (int g = 0; g < 16; ++g) gacc[g] = 0.0;
        for (int k = 0; k < 256; ++k) {
            double hd = (double)hp[k];
#pragma unroll
            for (int g = 0; g < 16; ++g) gacc[g] = fma(hd, g1s[k][g], gacc[g]);
        }
        double z = (double)g2b[0];
#pragma unroll
        for (int g = 0; g < 16; ++g) {
            double sg = gacc[g] + (double)g1b[g];
            sg = sg > 0.0 ? sg : 0.0;
            z = fma(sg, (double)g2w[g], z);
        }
        long long uz = __double_as_longlong(z);
        unsigned long long key = (uz < 0)
            ? ~((unsigned long long)uz)
            : ((unsigned long long)uz | 0x8000000000000000ULL);
        cand_keys[b * CANDCAP + slot] = key;
    }
}

// ---------------------------------------------------------------------------
// k3s: exact kth-largest among candidate f64 keys; write band masks; build
// masked-row compact list.
__global__ __launch_bounds__(1024) void k3s_select(
    const int* __restrict__ kptr,
    const int* __restrict__ cand_cnt,
    const int* __restrict__ cand_rows,
    const unsigned long long* __restrict__ cand_keys,
    float* __restrict__ maskout,
    int* __restrict__ ccnt,
    int* __restrict__ compact)
{
    __shared__ unsigned long long kbuf[CANDCAP];   // 32 KB
    __shared__ int s_cnt;

    const int b    = blockIdx.x;
    const int tid  = threadIdx.x;
    const int lane = tid & 63;
    const int n = min(cand_cnt[b], CANDCAP);
    const size_t bbase = (size_t)b * MM;
    int kval = min(*kptr, MM);
    if (kval > n) kval = n;   // safety (analysis: n ~ 2200 >> k)

    for (int i = tid; i < n; i += 1024) kbuf[i] = cand_keys[b * CANDCAP + i];
    __syncthreads();

    unsigned long long p64 = 0;
    int kk = kval;
    for (int bit = 63; bit >= 0; --bit) {
        if (tid == 0) s_cnt = 0;
        __syncthreads();
        unsigned long long himask = (bit == 63) ? 0ull : (~0ull << (bit + 1));
        int loc = 0;
        for (int i = tid; i < n; i += 1024) {
            unsigned long long x = kbuf[i];
            if (((x ^ p64) & himask) == 0ull && ((x >> bit) & 1ull)) loc++;
        }
        loc += __shfl_xor(loc, 32, 64);
        loc += __shfl_xor(loc, 16, 64);
        loc += __shfl_xor(loc, 8, 64);
        loc += __shfl_xor(loc, 4, 64);
        loc += __shfl_xor(loc, 2, 64);
        loc += __shfl_xor(loc, 1, 64);
        if (lane == 0 && loc) atomicAdd(&s_cnt, loc);
        __syncthreads();
        int c1 = s_cnt;
        if (c1 >= kk) p64 |= (1ull << bit); else kk -= c1;
        __syncthreads();
    }

    // masks + compact list for in-mask rows
    for (int i0 = 0; i0 < n; i0 += 1024) {
        int i = i0 + tid;
        bool active = (i < n);
        bool mk = false;
        int row = 0;
        if (active) {
            row = cand_rows[b * CANDCAP + i];
            mk = (kbuf[i] >= p64);
            maskout[bbase + row] = mk ? 1.0f : 0.0f;
        }
        unsigned long long ball = __ballot(mk);
        int wbase = 0;
        if (lane == 0) { int wc = __popcll(ball); if (wc) wbase = atomicAdd(&ccnt[b], wc); }
        wbase = __shfl(wbase, 0, 64);
        if (mk) {
            int pos = wbase + __popcll(ball & ((1ull << lane) - 1ull));
            if (pos < COMPCAP) compact[b * COMPCAP + pos] = row;
        }
    }
}

// ---------------------------------------------------------------------------
// k4: recompute A for masked rows; Ucorr[b][h][d] += (exp(A)-1)*h; Zcorr.
__global__ __launch_bounds__(256) void k4_corr(
    const float* __restrict__ h,
    const float* __restrict__ att_w,   // [256][8]
    const float* __restrict__ att_b,   // [8]
    const int* __restrict__ compact,
    const int* __restrict__ ccnt,
    double* __restrict__ Ucorr,
    double* __restrict__ Zcorr)
{
    __shared__ float hv_s[256];
    __shared__ float a_s[8];

    const int b    = blockIdx.x >> 5;
    const int part = blockIdx.x & 31;
    const int tid  = threadIdx.x;
    const int head = tid >> 5;
    const int seg  = tid & 31;
    const size_t bbase = (size_t)b * MM;
    const int n = min(ccnt[b], COMPCAP);

    float acc[8], zac[8];
#pragma unroll
    for (int j = 0; j < 8; ++j) { acc[j] = 0.f; zac[j] = 0.f; }

    for (int i = part; i < n; i += 32) {
        int row = compact[b * COMPCAP + i];
        float hv = h[(bbase + (size_t)row) * 256 + tid];
        hv_s[tid] = hv;
        __syncthreads();
        float p = 0.f;
#pragma unroll
        for (int j = 0; j < 8; ++j)
            p = fmaf(hv_s[seg * 8 + j], att_w[(seg * 8 + j) * 8 + head], p);
        p += __shfl_xor(p, 1, 64);
        p += __shfl_xor(p, 2, 64);
        p += __shfl_xor(p, 4, 64);
        p += __shfl_xor(p, 8, 64);
        p += __shfl_xor(p, 16, 64);
        if (seg == 0) a_s[head] = fmaxf(p + att_b[head], 0.f);
        __syncthreads();
#pragma unroll
        for (int j = 0; j < 8; ++j) {
            float w8 = expf(a_s[j]) - 1.0f;
            acc[j] = fmaf(w8, hv, acc[j]);
            zac[j] += w8;
        }
        __syncthreads();
    }
#pragma unroll
    for (int j = 0; j < 8; ++j)
        atomicAdd(&Ucorr[(b * 8 + j) * 256 + tid], (double)acc[j]);
    if (tid == 0) {
#pragma unroll
        for (int j = 0; j < 8; ++j) atomicAdd(&Zcorr[b * 8 + j], (double)zac[j]);
    }
}

// ---------------------------------------------------------------------------
// k5: epilogue
__global__ __launch_bounds__(256) void k5_final(
    const double* __restrict__ sumh,
    const double* __restrict__ Ucorr,
    const double* __restrict__ Zcorr,
    const int* __restrict__ ccnt,
    const float* __restrict__ w_w,     // [256][256]
    const float* __restrict__ res_w,   // [256][256]
    const float* __restrict__ res_b,   // [256]
    float* __restrict__ out0)
{
    __shared__ float Us[8 * 256];
    __shared__ float ms[256];
    __shared__ float red[256];
    __shared__ float s_mean, s_var;

    int b = blockIdx.x, e = threadIdx.x;
    double sh = sumh[b * 256 + e];
    ms[e] = (float)sh;
#pragma unroll
    for (int j = 0; j < 8; ++j)
        Us[j * 256 + e] = (float)(sh + Ucorr[(b * 8 + j) * 256 + e]);
    __syncthreads();

    int hh = e >> 5;
    float Z = (float)((double)(MM - ccnt[b]) + Zcorr[b * 8 + hh]);
    float attn = 0.f, qr = 0.f;
    for (int d = 0; d < 256; ++d) {
        attn = fmaf(Us[hh * 256 + d], w_w[d * 256 + e], attn);
        qr   = fmaf(ms[d],            res_w[d * 256 + e], qr);
    }
    float qres = fmaxf(qr * (1.0f / (float)MM) + res_b[e], 0.f);
    float pre  = fmaxf(attn / Z + qres, 0.f);

    red[e] = pre; __syncthreads();
    for (int s = 128; s > 0; s >>= 1) { if (e < s) red[e] += red[e + s]; __syncthreads(); }
    if (e == 0) s_mean = red[0] * (1.0f / 256.0f);
    __syncthreads();
    float mean = s_mean;
    float dv = pre - mean;
    red[e] = dv * dv; __syncthreads();
    for (int s = 128; s > 0; s >>= 1) { if (e < s) red[e] += red[e + s]; __syncthreads(); }
    if (e == 0) s_var = red[0] * (1.0f / 256.0f);
    __syncthreads();
    out0[b * 256 + e] = dv / sqrtf(s_var + 1e-8f);
}

// ---------------------------------------------------------------------------
extern "C" void kernel_launch(void* const* d_in, const int* in_sizes, int n_in,
                              void* d_out, int out_size, void* d_ws, size_t ws_size,
                              hipStream_t stream) {
    const float* h     = (const float*)d_in[0];
    const float* att_w = (const float*)d_in[1];
    const float* att_b = (const float*)d_in[2];
    const float* w_w   = (const float*)d_in[3];
    const float* res_w = (const float*)d_in[4];
    const float* res_b = (const float*)d_in[5];
    const float* g1w   = (const float*)d_in[6];
    const float* g1b   = (const float*)d_in[7];
    const float* g2w   = (const float*)d_in[8];
    const float* g2b   = (const float*)d_in[9];
    const int*   kptr  = (const int*)d_in[10];

    char* ws = (char*)d_ws;
    float*              z32     = (float*)(ws + OFF_Z);
    int*                candr   = (int*)(ws + OFF_CANDR);
    unsigned long long* candk   = (unsigned long long*)(ws + OFF_CANDK);
    int*                compact = (int*)(ws + OFF_COMP);
    unsigned int*       lo      = (unsigned int*)(ws + OFF_LO);
    double*             sumh    = (double*)(ws + OFF_SUMH);
    double*             Ucorr   = (double*)(ws + OFF_UCORR);
    double*             Zcorr   = (double*)(ws + OFF_ZCORR);
    int*                ccnt    = (int*)(ws + OFF_CCNT);
    int*                candc   = (int*)(ws + OFF_CANDC);

    float* out0    = (float*)d_out;
    float* maskout = out0 + BATCH * 256;

    hipMemsetAsync(ws + ZERO_OFF, 0, ZERO_SZ, stream);

    k1_main   <<<BATCH*TILES, 256,  0, stream>>>(h, g1w, g1b, g2w, g2b, z32, sumh);
    k2_sample <<<BATCH,       1024, 0, stream>>>(z32, kptr, lo);
    k3_band   <<<BATCH*TILES, 256,  0, stream>>>(z32, lo, maskout, candc, candr);
    k3r_refine<<<BATCH*16,    256,  0, stream>>>(h, g1w, g1b, g2w, g2b,
                                                 candc, candr, candk);
    k3s_select<<<BATCH,       1024, 0, stream>>>(kptr, candc, candr, candk,
                                                 maskout, ccnt, compact);
    k4_corr   <<<BATCH*32,    256,  0, stream>>>(h, att_w, att_b, compact, ccnt,
                                                 Ucorr, Zcorr);
    k5_final  <<<BATCH,       256,  0, stream>>>(sumh, Ucorr, Zcorr, ccnt,
                                                 w_w, res_w, res_b, out0);
}